// Round 6
// baseline (924.431 us; speedup 1.0000x reference)
//
#include <hip/hip_runtime.h>
#include <hip/hip_bf16.h>

typedef unsigned short u16;
typedef __attribute__((ext_vector_type(8))) short short8;
typedef __attribute__((ext_vector_type(4))) float f32x4;

constexpr int SEQ = 2048;
constexpr int NH  = 16;
constexpr int HD  = 64;
constexpr float SCALE = 0.125f;   // 1/sqrt(64)

constexpr int KP = 72;   // K tile [64][KP] bf16 (144B pitch)
constexpr int PP = 68;   // P tile [16][PP] bf16 (136B pitch -> lhi banks {0,8,16,24})
// Vt: [64 d][64 k] bf16, 128B pitch, granule-XOR swizzled by (d&7)

__device__ __forceinline__ f32x4 mfma16(short8 a, short8 b, f32x4 c) {
    return __builtin_amdgcn_mfma_f32_16x16x32_bf16(a, b, c, 0, 0, 0);
}

__device__ __forceinline__ u16 bf16r(float x) {
    __hip_bfloat16 h = __float2bfloat16(x);
    return *reinterpret_cast<u16*>(&h);
}

__device__ __forceinline__ short8 pack8(float4 a, float4 b) {
    short8 r;
    r[0] = (short)bf16r(a.x); r[1] = (short)bf16r(a.y);
    r[2] = (short)bf16r(a.z); r[3] = (short)bf16r(a.w);
    r[4] = (short)bf16r(b.x); r[5] = (short)bf16r(b.y);
    r[6] = (short)bf16r(b.z); r[7] = (short)bf16r(b.w);
    return r;
}

__global__ __launch_bounds__(256, 4)
void attn_fwd_kernel(const float* __restrict__ qkv, float* __restrict__ out) {
    __shared__ u16 Ks[64 * KP];
    __shared__ u16 Vt[64 * 64];
    __shared__ u16 Ps[4][2][16 * PP];   // [wave][qtile][16 rows]

    // XCD-aware swizzle: 8 consecutive bh share one XCD's L2
    const int orig = blockIdx.x;                 // nwg = 1024, %8==0 -> bijective
    const int v    = (orig & 7) * 128 + (orig >> 3);
    const int bh   = v >> 4;
    const int p    = v & 15;                     // pair id: q-tiles {p, 31-p}
    const int b    = bh >> 4;
    const int h    = bh & 15;

    const int tid  = threadIdx.x;
    const int wave = tid >> 6;
    const int lane = tid & 63;
    const int llo  = lane & 15;
    const int lhi  = lane >> 4;

    const int q0[2] = { p * 64 + wave * 16, (31 - p) * 64 + wave * 16 };
    const size_t basebh = (size_t)b * SEQ * 3072 + (size_t)h * HD;

    // ---- Q fragments (bf16) for both q-tiles, in registers all kernel ----
    short8 qf[2][2];
#pragma unroll
    for (int t = 0; t < 2; ++t) {
        const float* qp = qkv + basebh + (size_t)(q0[t] + llo) * 3072 + lhi * 8;
        qf[t][0] = pack8(*(const float4*)qp,        *(const float4*)(qp + 4));
        qf[t][1] = pack8(*(const float4*)(qp + 32), *(const float4*)(qp + 36));
    }

    f32x4 acc[2][4] = {};
    float m_r[2][4], l_r[2][4];
#pragma unroll
    for (int t = 0; t < 2; ++t)
#pragma unroll
        for (int r = 0; r < 4; ++r) { m_r[t][r] = -INFINITY; l_r[t][r] = 0.f; }

    // ---- staging thread roles ----
    const int kr  = tid >> 2;            // K row 0..63
    const int kc  = (tid & 3) * 16;      // K col {0,16,32,48}
    const int vd  = tid & 63;            // V column (d)
    const int vrg = tid >> 6;            // V 16-row group
    const float* kpg = qkv + basebh + (size_t)kr * 3072 + 1024 + kc;
    const float* vpg = qkv + basebh + (size_t)(vrg * 16) * 3072 + 2048 + vd;

    float4 kA, kB, kC, kD;               // K prefetch (16 floats)
    float  vr[16];                       // V prefetch (16 floats, strided rows)

#define LOADK(KT) { const float* pk_ = kpg + (size_t)(KT) * 64 * 3072;          \
        kA = *(const float4*)pk_;       kB = *(const float4*)(pk_ + 4);         \
        kC = *(const float4*)(pk_ + 8); kD = *(const float4*)(pk_ + 12); }
#define LOADV(KT) { const float* pv_ = vpg + (size_t)(KT) * 64 * 3072;          \
        _Pragma("unroll") for (int j_ = 0; j_ < 16; ++j_) vr[j_] = pv_[j_ * 3072]; }

    LOADK(0);
    LOADV(0);

    const int NT = 32 - p;               // k-tiles of 64 (covers both q-tiles)
    for (int kt = 0; kt < NT; ++kt) {
        const int kbase = kt * 64;
        __syncthreads();                 // prior tile's LDS consumers done
        // ---- write staged registers -> LDS (cvt fp32->bf16 here) ----
        *(short8*)&Ks[kr * KP + kc]     = pack8(kA, kB);
        *(short8*)&Ks[kr * KP + kc + 8] = pack8(kC, kD);
        {
            short8 p0, p1;
#pragma unroll
            for (int j = 0; j < 8; ++j) {
                p0[j] = (short)bf16r(vr[j]);
                p1[j] = (short)bf16r(vr[8 + j]);
            }
            char* vb = (char*)Vt + vd * 128;
            *(short8*)(vb + ((vrg * 32)      ^ ((vd & 7) << 4))) = p0;
            *(short8*)(vb + ((vrg * 32 + 16) ^ ((vd & 7) << 4))) = p1;
        }
        __syncthreads();
        if (kt + 1 < NT) LOADK(kt + 1);  // issue next K loads; latency hidden by QK^T

        const bool act0 = (kt <= p);     // t=1 always active

        // ---- QK^T: K fragments read ONCE, used by both q-tiles ----
        float pv[2][4][4];
#pragma unroll
        for (int cg = 0; cg < 4; ++cg) {
            const u16* kb = &Ks[(cg * 16 + llo) * KP + lhi * 8];
            short8 kf0 = *(const short8*)(kb);
            short8 kf1 = *(const short8*)(kb + 32);
            f32x4 s1 = {0.f, 0.f, 0.f, 0.f};
            s1 = mfma16(qf[1][0], kf0, s1);
            s1 = mfma16(qf[1][1], kf1, s1);
#pragma unroll
            for (int r = 0; r < 4; ++r) pv[1][cg][r] = s1[r];
            if (act0) {
                f32x4 s0 = {0.f, 0.f, 0.f, 0.f};
                s0 = mfma16(qf[0][0], kf0, s0);
                s0 = mfma16(qf[0][1], kf1, s0);
#pragma unroll
                for (int r = 0; r < 4; ++r) pv[0][cg][r] = s0[r];
            }
        }

        // ---- per-q-tile softmax + P store ----
#pragma unroll
        for (int t = 0; t < 2; ++t) {
            if (t == 0 && !act0) continue;
            float pmax[4];
#pragma unroll
            for (int r = 0; r < 4; ++r) pmax[r] = -INFINITY;
#pragma unroll
            for (int cg = 0; cg < 4; ++cg) {
                const int kj = kbase + cg * 16 + llo;
#pragma unroll
                for (int r = 0; r < 4; ++r) {
                    const int qi = q0[t] + lhi * 4 + r;  // C/D: row=(lane>>4)*4+r, col=lane&15
                    float sv = pv[t][cg][r] * SCALE;
                    sv = (kj > qi) ? -INFINITY : sv;
                    pv[t][cg][r] = sv;
                    pmax[r] = fmaxf(pmax[r], sv);
                }
            }
#pragma unroll
            for (int off = 1; off < 16; off <<= 1)
#pragma unroll
                for (int r = 0; r < 4; ++r)
                    pmax[r] = fmaxf(pmax[r], __shfl_xor(pmax[r], off, 64));

            float alpha[4], psum[4];
#pragma unroll
            for (int r = 0; r < 4; ++r) {
                float mn = fmaxf(m_r[t][r], pmax[r]);
                alpha[r] = __expf(m_r[t][r] - mn);
                m_r[t][r] = mn;
                float s0 = 0.f;
#pragma unroll
                for (int cg = 0; cg < 4; ++cg) {
                    pv[t][cg][r] = __expf(pv[t][cg][r] - mn);
                    s0 += pv[t][cg][r];
                }
                psum[r] = s0;
            }
#pragma unroll
            for (int off = 1; off < 16; off <<= 1)
#pragma unroll
                for (int r = 0; r < 4; ++r)
                    psum[r] += __shfl_xor(psum[r], off, 64);
#pragma unroll
            for (int r = 0; r < 4; ++r) l_r[t][r] = l_r[t][r] * alpha[r] + psum[r];
#pragma unroll
            for (int dc = 0; dc < 4; ++dc)
#pragma unroll
                for (int r = 0; r < 4; ++r)
                    acc[t][dc][r] *= alpha[r];

            u16* pw = Ps[wave][t];
#pragma unroll
            for (int cg = 0; cg < 4; ++cg)
#pragma unroll
                for (int r = 0; r < 4; ++r)
                    pw[(lhi * 4 + r) * PP + cg * 16 + llo] = bf16r(pv[t][cg][r]);
        }

        if (kt + 1 < NT) LOADV(kt + 1);  // issue next V loads; latency hidden by PV

        // ---- PV: V fragments read ONCE, used by both q-tiles ----
#pragma unroll
        for (int ks = 0; ks < 2; ++ks) {
            short8 pf1 = *(const short8*)&Ps[wave][1][llo * PP + ks * 32 + lhi * 8];
            short8 pf0 = pf1;
            if (act0) pf0 = *(const short8*)&Ps[wave][0][llo * PP + ks * 32 + lhi * 8];
#pragma unroll
            for (int dc = 0; dc < 4; ++dc) {
                const char* vsrc = (const char*)Vt + (dc * 16 + llo) * 128 +
                                   ((ks * 64 + lhi * 16) ^ ((llo & 7) << 4));
                short8 vf = *(const short8*)vsrc;
                acc[1][dc] = mfma16(pf1, vf, acc[1][dc]);
                if (act0) acc[0][dc] = mfma16(pf0, vf, acc[0][dc]);
            }
        }
    }

    // ---- epilogue: divide by l, write fp32 ----
#pragma unroll
    for (int t = 0; t < 2; ++t)
#pragma unroll
        for (int dc = 0; dc < 4; ++dc)
#pragma unroll
            for (int r = 0; r < 4; ++r) {
                const int qi = q0[t] + lhi * 4 + r;
                const int d  = dc * 16 + llo;
                out[((size_t)b * SEQ + qi) * (NH * HD) + h * HD + d] = acc[t][dc][r] / l_r[t][r];
            }
}

extern "C" void kernel_launch(void* const* d_in, const int* in_sizes, int n_in,
                              void* d_out, int out_size, void* d_ws, size_t ws_size,
                              hipStream_t stream) {
    const float* qkv = (const float*)d_in[0];
    float* out = (float*)d_out;
    const int B = in_sizes[0] / (SEQ * 3 * NH * HD);   // = 4
    dim3 grid(B * NH * 16);                            // 1024 blocks
    dim3 block(256);
    attn_fwd_kernel<<<grid, block, 0, stream>>>(qkv, out);
}

// Round 7
// 267.426 us; speedup vs baseline: 3.4568x; 3.4568x over previous
//
#include <hip/hip_runtime.h>
#include <hip/hip_bf16.h>

typedef unsigned short u16;
typedef __attribute__((ext_vector_type(8))) short short8;
typedef __attribute__((ext_vector_type(4))) float f32x4;

constexpr int SEQ = 2048;
constexpr int NH  = 16;
constexpr int HD  = 64;
constexpr float SCALE = 0.125f;   // 1/sqrt(64)

constexpr int KP = 72;   // K tile [64][KP] bf16 (144B pitch)
constexpr int PP = 68;   // P tile [16][PP] bf16 (136B pitch -> lhi banks {0,8,16,24})
// Vt: [64 d][64 k] bf16, 128B pitch, granule-XOR swizzled by (d&7)

__device__ __forceinline__ f32x4 mfma16(short8 a, short8 b, f32x4 c) {
    return __builtin_amdgcn_mfma_f32_16x16x32_bf16(a, b, c, 0, 0, 0);
}

__device__ __forceinline__ u16 bf16r(float x) {
    __hip_bfloat16 h = __float2bfloat16(x);
    return *reinterpret_cast<u16*>(&h);
}

__device__ __forceinline__ short8 pack8(float4 a, float4 b) {
    short8 r;
    r[0] = (short)bf16r(a.x); r[1] = (short)bf16r(a.y);
    r[2] = (short)bf16r(a.z); r[3] = (short)bf16r(a.w);
    r[4] = (short)bf16r(b.x); r[5] = (short)bf16r(b.y);
    r[6] = (short)bf16r(b.z); r[7] = (short)bf16r(b.w);
    return r;
}

// launch_bounds(256,4) capped unified VGPR+AGPR at 128/wave -> the 32 prefetch
// regs spilled to scratch (R6: WRITE_SIZE 1.3GB vs 33MB output). (256,2) lifts
// the cap to 256; LDS (34KB) still allows up to 4 blocks/CU, VGPR will limit ~3.
__global__ __launch_bounds__(256, 2)
void attn_fwd_kernel(const float* __restrict__ qkv, float* __restrict__ out) {
    __shared__ u16 Ks[64 * KP];
    __shared__ u16 Vt[64 * 64];
    __shared__ u16 Ps[4][2][16 * PP];   // [wave][qtile][16 rows]

    // XCD-aware swizzle: 8 consecutive bh share one XCD's L2
    const int orig = blockIdx.x;                 // nwg = 1024, %8==0 -> bijective
    const int v    = (orig & 7) * 128 + (orig >> 3);
    const int bh   = v >> 4;
    const int p    = v & 15;                     // pair id: q-tiles {p, 31-p}
    const int b    = bh >> 4;
    const int h    = bh & 15;

    const int tid  = threadIdx.x;
    const int wave = tid >> 6;
    const int lane = tid & 63;
    const int llo  = lane & 15;
    const int lhi  = lane >> 4;

    const int q0[2] = { p * 64 + wave * 16, (31 - p) * 64 + wave * 16 };
    const size_t basebh = (size_t)b * SEQ * 3072 + (size_t)h * HD;

    // ---- Q fragments (bf16) for both q-tiles, in registers all kernel ----
    short8 qf[2][2];
#pragma unroll
    for (int t = 0; t < 2; ++t) {
        const float* qp = qkv + basebh + (size_t)(q0[t] + llo) * 3072 + lhi * 8;
        qf[t][0] = pack8(*(const float4*)qp,        *(const float4*)(qp + 4));
        qf[t][1] = pack8(*(const float4*)(qp + 32), *(const float4*)(qp + 36));
    }

    f32x4 acc[2][4] = {};
    float m_r[2][4], l_r[2][4];
#pragma unroll
    for (int t = 0; t < 2; ++t)
#pragma unroll
        for (int r = 0; r < 4; ++r) { m_r[t][r] = -INFINITY; l_r[t][r] = 0.f; }

    // ---- staging thread roles ----
    const int kr  = tid >> 2;            // K row 0..63
    const int kc  = (tid & 3) * 16;      // K col {0,16,32,48}
    const int vd  = tid & 63;            // V column (d)
    const int vrg = tid >> 6;            // V 16-row group
    const float* kpg = qkv + basebh + (size_t)kr * 3072 + 1024 + kc;
    const float* vpg = qkv + basebh + (size_t)(vrg * 16) * 3072 + 2048 + vd;

    float4 kA, kB, kC, kD;               // K prefetch (16 floats)
    float  vr[16];                       // V prefetch (16 floats, strided rows)

#define LOADK(KT) { const float* pk_ = kpg + (size_t)(KT) * 64 * 3072;          \
        kA = *(const float4*)pk_;       kB = *(const float4*)(pk_ + 4);         \
        kC = *(const float4*)(pk_ + 8); kD = *(const float4*)(pk_ + 12); }
#define LOADV(KT) { const float* pv_ = vpg + (size_t)(KT) * 64 * 3072;          \
        _Pragma("unroll") for (int j_ = 0; j_ < 16; ++j_) vr[j_] = pv_[j_ * 3072]; }

    LOADK(0);
    LOADV(0);

    const int NT = 32 - p;               // k-tiles of 64 (covers both q-tiles)
    for (int kt = 0; kt < NT; ++kt) {
        const int kbase = kt * 64;
        __syncthreads();                 // prior tile's LDS consumers done
        // ---- write staged registers -> LDS (cvt fp32->bf16 here) ----
        *(short8*)&Ks[kr * KP + kc]     = pack8(kA, kB);
        *(short8*)&Ks[kr * KP + kc + 8] = pack8(kC, kD);
        {
            short8 p0, p1;
#pragma unroll
            for (int j = 0; j < 8; ++j) {
                p0[j] = (short)bf16r(vr[j]);
                p1[j] = (short)bf16r(vr[8 + j]);
            }
            char* vb = (char*)Vt + vd * 128;
            *(short8*)(vb + ((vrg * 32)      ^ ((vd & 7) << 4))) = p0;
            *(short8*)(vb + ((vrg * 32 + 16) ^ ((vd & 7) << 4))) = p1;
        }
        __syncthreads();
        if (kt + 1 < NT) LOADK(kt + 1);  // issue next K loads; latency hidden by QK^T

        const bool act0 = (kt <= p);     // t=1 always active

        // ---- QK^T: K fragments read ONCE, used by both q-tiles ----
        float pv[2][4][4];
#pragma unroll
        for (int cg = 0; cg < 4; ++cg) {
            const u16* kb = &Ks[(cg * 16 + llo) * KP + lhi * 8];
            short8 kf0 = *(const short8*)(kb);
            short8 kf1 = *(const short8*)(kb + 32);
            f32x4 s1 = {0.f, 0.f, 0.f, 0.f};
            s1 = mfma16(qf[1][0], kf0, s1);
            s1 = mfma16(qf[1][1], kf1, s1);
#pragma unroll
            for (int r = 0; r < 4; ++r) pv[1][cg][r] = s1[r];
            if (act0) {
                f32x4 s0 = {0.f, 0.f, 0.f, 0.f};
                s0 = mfma16(qf[0][0], kf0, s0);
                s0 = mfma16(qf[0][1], kf1, s0);
#pragma unroll
                for (int r = 0; r < 4; ++r) pv[0][cg][r] = s0[r];
            }
        }

        // ---- per-q-tile softmax + P store ----
#pragma unroll
        for (int t = 0; t < 2; ++t) {
            if (t == 0 && !act0) continue;
            float pmax[4];
#pragma unroll
            for (int r = 0; r < 4; ++r) pmax[r] = -INFINITY;
#pragma unroll
            for (int cg = 0; cg < 4; ++cg) {
                const int kj = kbase + cg * 16 + llo;
#pragma unroll
                for (int r = 0; r < 4; ++r) {
                    const int qi = q0[t] + lhi * 4 + r;  // C/D: row=(lane>>4)*4+r, col=lane&15
                    float sv = pv[t][cg][r] * SCALE;
                    sv = (kj > qi) ? -INFINITY : sv;
                    pv[t][cg][r] = sv;
                    pmax[r] = fmaxf(pmax[r], sv);
                }
            }
#pragma unroll
            for (int off = 1; off < 16; off <<= 1)
#pragma unroll
                for (int r = 0; r < 4; ++r)
                    pmax[r] = fmaxf(pmax[r], __shfl_xor(pmax[r], off, 64));

            float alpha[4], psum[4];
#pragma unroll
            for (int r = 0; r < 4; ++r) {
                float mn = fmaxf(m_r[t][r], pmax[r]);
                alpha[r] = __expf(m_r[t][r] - mn);
                m_r[t][r] = mn;
                float s0 = 0.f;
#pragma unroll
                for (int cg = 0; cg < 4; ++cg) {
                    pv[t][cg][r] = __expf(pv[t][cg][r] - mn);
                    s0 += pv[t][cg][r];
                }
                psum[r] = s0;
            }
#pragma unroll
            for (int off = 1; off < 16; off <<= 1)
#pragma unroll
                for (int r = 0; r < 4; ++r)
                    psum[r] += __shfl_xor(psum[r], off, 64);
#pragma unroll
            for (int r = 0; r < 4; ++r) l_r[t][r] = l_r[t][r] * alpha[r] + psum[r];
#pragma unroll
            for (int dc = 0; dc < 4; ++dc)
#pragma unroll
                for (int r = 0; r < 4; ++r)
                    acc[t][dc][r] *= alpha[r];

            u16* pw = Ps[wave][t];
#pragma unroll
            for (int cg = 0; cg < 4; ++cg)
#pragma unroll
                for (int r = 0; r < 4; ++r)
                    pw[(lhi * 4 + r) * PP + cg * 16 + llo] = bf16r(pv[t][cg][r]);
        }

        if (kt + 1 < NT) LOADV(kt + 1);  // issue next V loads; latency hidden by PV

        // ---- PV: V fragments read ONCE, used by both q-tiles ----
#pragma unroll
        for (int ks = 0; ks < 2; ++ks) {
            short8 pf1 = *(const short8*)&Ps[wave][1][llo * PP + ks * 32 + lhi * 8];
            short8 pf0 = pf1;
            if (act0) pf0 = *(const short8*)&Ps[wave][0][llo * PP + ks * 32 + lhi * 8];
#pragma unroll
            for (int dc = 0; dc < 4; ++dc) {
                const char* vsrc = (const char*)Vt + (dc * 16 + llo) * 128 +
                                   ((ks * 64 + lhi * 16) ^ ((llo & 7) << 4));
                short8 vf = *(const short8*)vsrc;
                acc[1][dc] = mfma16(pf1, vf, acc[1][dc]);
                if (act0) acc[0][dc] = mfma16(pf0, vf, acc[0][dc]);
            }
        }
    }

    // ---- epilogue: divide by l, write fp32 ----
#pragma unroll
    for (int t = 0; t < 2; ++t)
#pragma unroll
        for (int dc = 0; dc < 4; ++dc)
#pragma unroll
            for (int r = 0; r < 4; ++r) {
                const int qi = q0[t] + lhi * 4 + r;
                const int d  = dc * 16 + llo;
                out[((size_t)b * SEQ + qi) * (NH * HD) + h * HD + d] = acc[t][dc][r] / l_r[t][r];
            }
}

extern "C" void kernel_launch(void* const* d_in, const int* in_sizes, int n_in,
                              void* d_out, int out_size, void* d_ws, size_t ws_size,
                              hipStream_t stream) {
    const float* qkv = (const float*)d_in[0];
    float* out = (float*)d_out;
    const int B = in_sizes[0] / (SEQ * 3 * NH * HD);   // = 4
    dim3 grid(B * NH * 16);                            // 1024 blocks
    dim3 block(256);
    attn_fwd_kernel<<<grid, block, 0, stream>>>(qkv, out);
}